// Round 3
// baseline (258.663 us; speedup 1.0000x reference)
//
#include <hip/hip_runtime.h>
#include <math.h>

// Peak biquad (DF2T) over (16, 2, 1<<20) fp32.
//
// R2 result: coalesced LDS staging fixed write amplification but hit only
// 2.55 TB/s — each wave's load->syncthreads(vmcnt(0) drain)->compute->store
// cycle leaves HBM idle ~2/3 of the time.
// R3: one wave per block => replace __syncthreads with a compiler-level
// fence (asm memory clobber + wave_barrier; CDNA LDS ops from one wave
// complete in issue order, so no s_barrier / vmcnt drain is needed).
// Each block walks a run of 8 consecutive 16-KiB tiles with double-buffered
// LDS: loads for tile i+1 issue before the ~2000-cycle recurrence on tile i,
// keeping ~17 KB/wave of reads continuously in flight (4 waves/CU).

constexpr int T_LEN   = 1 << 20;          // samples per channel
constexpr int L_G     = 16;               // granules (float4) per chunk = 64 samples
constexpr int THREADS = 64;               // one wave per block
constexpr int RS      = L_G + 1;          // LDS row stride (pad kills pow2 conflicts)
constexpr int ROWS    = THREADS + 1;      // halo row + 64 chunk rows
constexpr int GPB     = THREADS * L_G;    // 1024 granules per tile (16 KiB)
constexpr int TILES_PER_CHAN = (T_LEN / 4) / GPB;   // 256
constexpr int RUN     = 8;                // tiles per block (256 % 8 == 0 -> runs
                                          // never straddle a channel boundary)

// Compiler-only ordering fence for intra-wave LDS cross-lane hand-offs.
// No hardware cost: LDS ops from a single wave execute in issue order; we
// only need to stop the compiler from reordering may-not-alias DS ops.
#define WAVE_FENCE() do { asm volatile("" ::: "memory"); \
                          __builtin_amdgcn_wave_barrier(); } while (0)

__global__ __launch_bounds__(THREADS) void peak_kernel(
    const float4* __restrict__ x4,
    const float* __restrict__ p_freq_raw,
    const float* __restrict__ p_q_raw,
    const float* __restrict__ p_gain,
    float4* __restrict__ y4)
{
    // rows: 0 = halo (last chunk before tile), 1..64 = this tile's chunks
    __shared__ float4 lds[2][ROWS * RS];   // 2 x 17,680 B = 35,360 B -> 4 blk/CU

    const int t = threadIdx.x;
    size_t tile = (size_t)blockIdx.x * RUN;
    size_t base = tile * GPB;
    const bool chan_start = (tile % TILES_PER_CHAN) == 0;

    // ---- coefficients (scalar, once per 32k samples of work) ----
    float fraw = p_freq_raw[0];
    float qraw = p_q_raw[0];
    float gdb  = p_gain[0];

    float sfreq = 1.0f / (1.0f + __expf(-fraw));
    float freq  = sfreq * (17500.0f - 33.0f) + 33.0f;
    float sq    = 1.0f / (1.0f + __expf(-qraw));
    float Q     = sq * (20.0f - 0.2f) + 0.2f;

    float w0    = 6.283185307179586f * freq / 44100.0f;
    float A     = expf(gdb * 0.05756462732485114f);   // 10^(g/40)
    float sw    = sinf(w0);
    float cw    = cosf(w0);
    float alpha = sw / (2.0f * Q);

    float inv_a0 = 1.0f / (1.0f + alpha / A);
    float b0  = (1.0f + alpha * A) * inv_a0;
    float b1  = (-2.0f * cw) * inv_a0;
    float b2  = (1.0f - alpha * A) * inv_a0;
    float na1 = -b1;
    float na2 = -((1.0f - alpha / A) * inv_a0);

    // ---- preload first tile of the run ----
    float4 ph = make_float4(0.f, 0.f, 0.f, 0.f);
    if (t < L_G && !chan_start) ph = x4[base - L_G + t];
    float4 pm[L_G];
    #pragma unroll
    for (int k = 0; k < L_G; ++k) pm[k] = x4[base + k * THREADS + t];

    if (t < L_G) lds[0][t] = ph;
    #pragma unroll
    for (int k = 0; k < L_G; ++k) {
        int g = k * THREADS + t;
        lds[0][(1 + (g >> 4)) * RS + (g & 15)] = pm[k];
    }
    WAVE_FENCE();

    int cur = 0;
    for (int i = 0; i < RUN; ++i) {
        size_t nbase = base + GPB;

        // ---- issue prefetch for tile i+1 (latency hidden under compute) ----
        if (i + 1 < RUN) {
            if (t < L_G) ph = x4[nbase - L_G + t];
            #pragma unroll
            for (int k = 0; k < L_G; ++k) pm[k] = x4[nbase + k * THREADS + t];
        }

        // ---- warm-up: previous chunk (row t), discard outputs ----
        float s1 = 0.0f, s2 = 0.0f;
        {
            const float4* wrow = &lds[cur][t * RS];
            #pragma unroll
            for (int j = 0; j < L_G; ++j) {
                float4 xv = wrow[j];
                #pragma unroll
                for (int q = 0; q < 4; ++q) {
                    float xt = (&xv.x)[q];
                    float yv = fmaf(b0, xt, s1);
                    s1 = fmaf(b1, xt, s2);
                    s1 = fmaf(na1, yv, s1);
                    s2 = xt * b2;
                    s2 = fmaf(na2, yv, s2);
                }
            }
        }
        WAVE_FENCE();   // all warm-up reads done before rows are overwritten

        // ---- main: own chunk (row t+1), overwrite x with y in place ----
        {
            float4* mrow = &lds[cur][(t + 1) * RS];
            #pragma unroll
            for (int j = 0; j < L_G; ++j) {
                float4 xv = mrow[j];
                float4 ov;
                #pragma unroll
                for (int q = 0; q < 4; ++q) {
                    float xt = (&xv.x)[q];
                    float yv = fmaf(b0, xt, s1);
                    s1 = fmaf(b1, xt, s2);
                    s1 = fmaf(na1, yv, s1);
                    s2 = xt * b2;
                    s2 = fmaf(na2, yv, s2);
                    (&ov.x)[q] = yv;
                }
                mrow[j] = ov;
            }
        }
        WAVE_FENCE();   // y complete in LDS before store phase reads it

        // ---- scatter prefetched tile i+1 into the other buffer ----
        // (vmcnt wait here covers loads issued ~2000 cycles ago - cheap)
        if (i + 1 < RUN) {
            int nxt = cur ^ 1;
            if (t < L_G) lds[nxt][t] = ph;
            #pragma unroll
            for (int k = 0; k < L_G; ++k) {
                int g = k * THREADS + t;
                lds[nxt][(1 + (g >> 4)) * RS + (g & 15)] = pm[k];
            }
        }

        // ---- coalesced LDS -> global store of y ----
        #pragma unroll
        for (int k = 0; k < L_G; ++k) {
            int g = k * THREADS + t;
            y4[base + g] = lds[cur][(1 + (g >> 4)) * RS + (g & 15)];
        }
        WAVE_FENCE();   // nxt buffer fully written before next iter reads it

        base = nbase;
        cur ^= 1;
    }
}

extern "C" void kernel_launch(void* const* d_in, const int* in_sizes, int n_in,
                              void* d_out, int out_size, void* d_ws, size_t ws_size,
                              hipStream_t stream)
{
    const float4* x4 = (const float4*)d_in[0];
    const float*  fr = (const float*)d_in[1];
    const float*  qr = (const float*)d_in[2];
    const float*  gn = (const float*)d_in[3];
    float4*       y4 = (float4*)d_out;

    int n_channels = in_sizes[0] / T_LEN;                    // 32
    int n_tiles    = n_channels * TILES_PER_CHAN;            // 8192
    int n_blocks   = n_tiles / RUN;                          // 1024

    hipLaunchKernelGGL(peak_kernel, dim3(n_blocks), dim3(THREADS), 0, stream,
                       x4, fr, qr, gn, y4);
}